// Round 1
// baseline (662.109 us; speedup 1.0000x reference)
//
#include <hip/hip_runtime.h>
#include <math.h>

// Problem constants (MicroGPT)
constexpr int Bc  = 16;
constexpr int Tc  = 2048;
constexpr int Cc  = 16;
constexpr int Hc  = 2;
constexpr int HSc = 8;
constexpr int Lc  = 2;
constexpr int Vc  = 256;
constexpr int BT  = Bc * Tc;          // 32768 tokens
constexpr float EPSc = 1e-5f;

// Attention tiling
constexpr int TQ  = 128;              // queries per block (= threads per block)
constexpr int NQT = Tc / TQ;          // 16 query tiles per (b,h)

// ---------------------------------------------------------------------------
// LN helper: 16-wide layernorm entirely in registers
// ---------------------------------------------------------------------------
__device__ inline void layernorm16(const float* xr, float* h,
                                   const float* g, const float* b) {
  float m = 0.f;
#pragma unroll
  for (int c = 0; c < Cc; c++) m += xr[c];
  m *= (1.f / Cc);
  float var = 0.f;
#pragma unroll
  for (int c = 0; c < Cc; c++) { float d = xr[c] - m; var += d * d; }
  var *= (1.f / Cc);
  float rs = rsqrtf(var + EPSc);
#pragma unroll
  for (int c = 0; c < Cc; c++) h[c] = (xr[c] - m) * rs * g[c] + b[c];
}

// ---------------------------------------------------------------------------
// 1) x[b,t,:] = tok_emb[idx[b,t],:] + pos_emb[t,:]
// ---------------------------------------------------------------------------
__global__ __launch_bounds__(256) void embed_kernel(
    const int* __restrict__ idx, const float* __restrict__ tok,
    const float* __restrict__ pos, float* __restrict__ x) {
  int t  = blockIdx.x * 256 + threadIdx.x;   // token id in [0, BT)
  int tt = t & (Tc - 1);
  int id = idx[t];
  const float4* te = (const float4*)(tok + id * Cc);
  const float4* pe = (const float4*)(pos + tt * Cc);
  float4* xo = (float4*)(x + t * Cc);
#pragma unroll
  for (int i = 0; i < 4; i++) {
    float4 a = te[i], b = pe[i];
    xo[i] = make_float4(a.x + b.x, a.y + b.y, a.z + b.z, a.w + b.w);
  }
}

// ---------------------------------------------------------------------------
// 2) h = LN1(x); q/k/v = h @ wq/wk/wv   (per-token thread, weights in LDS)
//    q,k,v layout: [B][H][T][HS]
// ---------------------------------------------------------------------------
__global__ __launch_bounds__(256) void ln_qkv_kernel(
    const float* __restrict__ x,
    const float* __restrict__ wq, const float* __restrict__ wk,
    const float* __restrict__ wv,
    const float* __restrict__ g, const float* __restrict__ b,
    float* __restrict__ q, float* __restrict__ k, float* __restrict__ v) {
  __shared__ float swq[Hc * Cc * HSc], swk[Hc * Cc * HSc], swv[Hc * Cc * HSc];
  __shared__ float sg[Cc], sb[Cc];
  int tid = threadIdx.x;
  swq[tid] = wq[tid];   // Hc*Cc*HSc == 256 == blockDim
  swk[tid] = wk[tid];
  swv[tid] = wv[tid];
  if (tid < Cc) { sg[tid] = g[tid]; sb[tid] = b[tid]; }
  __syncthreads();

  int tok = blockIdx.x * 256 + tid;
  float xr[Cc];
  const float4* xp = (const float4*)(x + tok * Cc);
#pragma unroll
  for (int i = 0; i < 4; i++) {
    float4 a = xp[i];
    xr[4*i] = a.x; xr[4*i+1] = a.y; xr[4*i+2] = a.z; xr[4*i+3] = a.w;
  }
  float h[Cc];
  layernorm16(xr, h, sg, sb);

  int bb = tok >> 11;        // / Tc
  int tt = tok & (Tc - 1);
#pragma unroll
  for (int hh = 0; hh < Hc; hh++) {
    float oq[HSc], ok[HSc], ov[HSc];
#pragma unroll
    for (int s = 0; s < HSc; s++) { oq[s] = 0.f; ok[s] = 0.f; ov[s] = 0.f; }
#pragma unroll
    for (int c = 0; c < Cc; c++) {
      float hv = h[c];
      const float* wqp = swq + (hh * Cc + c) * HSc;
      const float* wkp = swk + (hh * Cc + c) * HSc;
      const float* wvp = swv + (hh * Cc + c) * HSc;
#pragma unroll
      for (int s = 0; s < HSc; s++) {
        oq[s] += hv * wqp[s];
        ok[s] += hv * wkp[s];
        ov[s] += hv * wvp[s];
      }
    }
    long base = ((long)(bb * Hc + hh) * Tc + tt) * HSc;
    ((float4*)(q + base))[0] = make_float4(oq[0], oq[1], oq[2], oq[3]);
    ((float4*)(q + base))[1] = make_float4(oq[4], oq[5], oq[6], oq[7]);
    ((float4*)(k + base))[0] = make_float4(ok[0], ok[1], ok[2], ok[3]);
    ((float4*)(k + base))[1] = make_float4(ok[4], ok[5], ok[6], ok[7]);
    ((float4*)(v + base))[0] = make_float4(ov[0], ov[1], ov[2], ov[3]);
    ((float4*)(v + base))[1] = make_float4(ov[4], ov[5], ov[6], ov[7]);
  }
}

// ---------------------------------------------------------------------------
// 3) Causal flash attention, thread-per-query, K/V tiles in LDS.
//    No max subtraction: |score| << 1 with these weight scales, exp cannot
//    overflow, and softmax is shift-invariant so result is identical.
//    o layout: [B][T][C] (heads concatenated)
// ---------------------------------------------------------------------------
__global__ __launch_bounds__(TQ) void attn_kernel(
    const float* __restrict__ q, const float* __restrict__ k,
    const float* __restrict__ v, float* __restrict__ o) {
  __shared__ float sk[TQ * HSc], sv[TQ * HSc];
  // LPT schedule: longest (highest qt) blocks dispatched first
  int bh = blockIdx.x & (Bc * Hc - 1);         // 32 (b,h) pairs
  int qt = NQT - 1 - (blockIdx.x >> 5);
  const float* kb = k + (long)bh * Tc * HSc;
  const float* vb = v + (long)bh * Tc * HSc;
  int tq = qt * TQ + threadIdx.x;

  float qr[HSc];
  const float4* qp = (const float4*)(q + ((long)bh * Tc + tq) * HSc);
  float4 q0 = qp[0], q1 = qp[1];
  qr[0] = q0.x; qr[1] = q0.y; qr[2] = q0.z; qr[3] = q0.w;
  qr[4] = q1.x; qr[5] = q1.y; qr[6] = q1.z; qr[7] = q1.w;
  const float scale = 0.3535533905932738f;     // 8^-0.5
#pragma unroll
  for (int i = 0; i < HSc; i++) qr[i] *= scale;

  float l = 0.f;
  float acc[HSc] = {0.f, 0.f, 0.f, 0.f, 0.f, 0.f, 0.f, 0.f};

  for (int kt = 0; kt <= qt; kt++) {
    __syncthreads();
    {
      const float4* ksrc = (const float4*)(kb + kt * TQ * HSc);
      const float4* vsrc = (const float4*)(vb + kt * TQ * HSc);
      float4* skp = (float4*)sk;
      float4* svp = (float4*)sv;
      skp[threadIdx.x]       = ksrc[threadIdx.x];
      skp[threadIdx.x + TQ]  = ksrc[threadIdx.x + TQ];
      svp[threadIdx.x]       = vsrc[threadIdx.x];
      svp[threadIdx.x + TQ]  = vsrc[threadIdx.x + TQ];
    }
    __syncthreads();
    int kmax = (kt < qt) ? TQ : ((int)threadIdx.x + 1);
    for (int u = 0; u < kmax; u++) {
      const float4* kr = (const float4*)(sk + u * HSc);
      float4 ka = kr[0], kb4 = kr[1];
      float s = qr[0]*ka.x + qr[1]*ka.y + qr[2]*ka.z + qr[3]*ka.w
              + qr[4]*kb4.x + qr[5]*kb4.y + qr[6]*kb4.z + qr[7]*kb4.w;
      float p = __expf(s);
      l += p;
      const float4* vr = (const float4*)(sv + u * HSc);
      float4 va = vr[0], vb4 = vr[1];
      acc[0] += p * va.x;  acc[1] += p * va.y;
      acc[2] += p * va.z;  acc[3] += p * va.w;
      acc[4] += p * vb4.x; acc[5] += p * vb4.y;
      acc[6] += p * vb4.z; acc[7] += p * vb4.w;
    }
  }
  float inv = 1.f / l;
  int bb = bh >> 1, hh = bh & 1;
  float* op = o + ((long)(bb * Tc + tq)) * Cc + hh * HSc;
  ((float4*)op)[0] = make_float4(acc[0]*inv, acc[1]*inv, acc[2]*inv, acc[3]*inv);
  ((float4*)op)[1] = make_float4(acc[4]*inv, acc[5]*inv, acc[6]*inv, acc[7]*inv);
}

// ---------------------------------------------------------------------------
// 4) x += o @ wo^T   (per-token thread, wo in LDS)
// ---------------------------------------------------------------------------
__global__ __launch_bounds__(256) void proj_kernel(
    const float* __restrict__ o, const float* __restrict__ wo,
    float* __restrict__ x) {
  __shared__ float sw[Cc * Cc];
  int tid = threadIdx.x;
  sw[tid] = wo[tid];      // 256
  __syncthreads();
  int tok = blockIdx.x * 256 + tid;
  float orow[Cc];
  const float4* op = (const float4*)(o + tok * Cc);
#pragma unroll
  for (int i = 0; i < 4; i++) {
    float4 a = op[i];
    orow[4*i] = a.x; orow[4*i+1] = a.y; orow[4*i+2] = a.z; orow[4*i+3] = a.w;
  }
  float4* xp = (float4*)(x + tok * Cc);
#pragma unroll
  for (int i = 0; i < 4; i++) {
    float4 xv = xp[i];
    float r[4];
#pragma unroll
    for (int j = 0; j < 4; j++) {
      int c = 4 * i + j;
      float acc = 0.f;
#pragma unroll
      for (int kk = 0; kk < Cc; kk++) acc += orow[kk] * sw[c * Cc + kk];
      r[j] = acc;
    }
    xp[i] = make_float4(xv.x + r[0], xv.y + r[1], xv.z + r[2], xv.w + r[3]);
  }
}

// ---------------------------------------------------------------------------
// 5) x += relu(LN2(x) @ w1^T) @ w2^T   (per-token thread, w1/w2 in LDS)
// ---------------------------------------------------------------------------
__global__ __launch_bounds__(256) void mlp_kernel(
    float* __restrict__ x, const float* __restrict__ w1,
    const float* __restrict__ w2,
    const float* __restrict__ g, const float* __restrict__ b) {
  __shared__ float sw1[4 * Cc * Cc], sw2[Cc * 4 * Cc];  // 1024 each
  __shared__ float sg[Cc], sb[Cc];
  int tid = threadIdx.x;
#pragma unroll
  for (int i = 0; i < 4; i++) {
    sw1[tid + i * 256] = w1[tid + i * 256];
    sw2[tid + i * 256] = w2[tid + i * 256];
  }
  if (tid < Cc) { sg[tid] = g[tid]; sb[tid] = b[tid]; }
  __syncthreads();

  int tok = blockIdx.x * 256 + tid;
  float xr[Cc];
  float4* xp = (float4*)(x + tok * Cc);
#pragma unroll
  for (int i = 0; i < 4; i++) {
    float4 a = xp[i];
    xr[4*i] = a.x; xr[4*i+1] = a.y; xr[4*i+2] = a.z; xr[4*i+3] = a.w;
  }
  float h[Cc];
  layernorm16(xr, h, sg, sb);

  float r[Cc];
#pragma unroll
  for (int c = 0; c < Cc; c++) r[c] = 0.f;
  for (int j = 0; j < 4 * Cc; j++) {
    float acc = 0.f;
#pragma unroll
    for (int c = 0; c < Cc; c++) acc += h[c] * sw1[j * Cc + c];
    acc = fmaxf(acc, 0.f);
#pragma unroll
    for (int c = 0; c < Cc; c++) r[c] += acc * sw2[c * 4 * Cc + j];
  }
#pragma unroll
  for (int i = 0; i < 4; i++) {
    xp[i] = make_float4(xr[4*i] + r[4*i], xr[4*i+1] + r[4*i+1],
                        xr[4*i+2] + r[4*i+2], xr[4*i+3] + r[4*i+3]);
  }
}

// ---------------------------------------------------------------------------
// 6) out = LNf(x) @ tok_emb^T   (16 rows per block; tok_emb^T in LDS)
// ---------------------------------------------------------------------------
__global__ __launch_bounds__(256) void head_kernel(
    const float* __restrict__ x, const float* __restrict__ tok,
    const float* __restrict__ g, const float* __restrict__ b,
    float* __restrict__ out) {
  __shared__ float sembT[Cc * Vc];   // [c][v], 16 KiB, conflict-free reads
  __shared__ float sh[16][Cc];
  int tid = threadIdx.x;             // == vocab id v
  const float4* ep = (const float4*)(tok + tid * Cc);
#pragma unroll
  for (int i = 0; i < 4; i++) {
    float4 a = ep[i];
    sembT[(4*i+0) * Vc + tid] = a.x;
    sembT[(4*i+1) * Vc + tid] = a.y;
    sembT[(4*i+2) * Vc + tid] = a.z;
    sembT[(4*i+3) * Vc + tid] = a.w;
  }
  int row0 = blockIdx.x * 16;
  if (tid < 16) {
    float xr[Cc];
    const float4* xp = (const float4*)(x + (long)(row0 + tid) * Cc);
#pragma unroll
    for (int i = 0; i < 4; i++) {
      float4 a = xp[i];
      xr[4*i] = a.x; xr[4*i+1] = a.y; xr[4*i+2] = a.z; xr[4*i+3] = a.w;
    }
    float gg[Cc], bb[Cc];
#pragma unroll
    for (int c = 0; c < Cc; c++) { gg[c] = g[c]; bb[c] = b[c]; }
    float h[Cc];
    layernorm16(xr, h, gg, bb);
#pragma unroll
    for (int c = 0; c < Cc; c++) sh[tid][c] = h[c];
  }
  __syncthreads();

  float e[Cc];
#pragma unroll
  for (int c = 0; c < Cc; c++) e[c] = sembT[c * Vc + tid];
#pragma unroll
  for (int r = 0; r < 16; r++) {
    float acc = 0.f;
#pragma unroll
    for (int c = 0; c < Cc; c++) acc += sh[r][c] * e[c];
    out[(long)(row0 + r) * Vc + tid] = acc;
  }
}

// ---------------------------------------------------------------------------
// launcher
// ---------------------------------------------------------------------------
extern "C" void kernel_launch(void* const* d_in, const int* in_sizes, int n_in,
                              void* d_out, int out_size, void* d_ws,
                              size_t ws_size, hipStream_t stream) {
  const int*   idx  = (const int*)  d_in[0];
  const float* tok  = (const float*)d_in[1];
  const float* pos  = (const float*)d_in[2];
  const float* wq   = (const float*)d_in[3];
  const float* wk   = (const float*)d_in[4];
  const float* wv   = (const float*)d_in[5];
  const float* wo   = (const float*)d_in[6];
  const float* ln1g = (const float*)d_in[7];
  const float* ln1b = (const float*)d_in[8];
  const float* ln2g = (const float*)d_in[9];
  const float* ln2b = (const float*)d_in[10];
  const float* w1   = (const float*)d_in[11];
  const float* w2   = (const float*)d_in[12];
  const float* lnfg = (const float*)d_in[13];
  const float* lnfb = (const float*)d_in[14];
  float* out = (float*)d_out;

  // workspace layout: 5 buffers of BT*16 floats (2 MB each, 10 MB total)
  float* x  = (float*)d_ws;
  float* q  = x + (long)BT * Cc;
  float* k  = q + (long)Bc * Hc * Tc * HSc;
  float* v  = k + (long)Bc * Hc * Tc * HSc;
  float* o  = v + (long)Bc * Hc * Tc * HSc;

  embed_kernel<<<BT / 256, 256, 0, stream>>>(idx, tok, pos, x);
  for (int l = 0; l < Lc; l++) {
    ln_qkv_kernel<<<BT / 256, 256, 0, stream>>>(
        x, wq + l * Hc * Cc * HSc, wk + l * Hc * Cc * HSc,
        wv + l * Hc * Cc * HSc, ln1g + l * Cc, ln1b + l * Cc, q, k, v);
    attn_kernel<<<Bc * Hc * NQT, TQ, 0, stream>>>(q, k, v, o);
    proj_kernel<<<BT / 256, 256, 0, stream>>>(o, wo + l * Cc * Cc, x);
    mlp_kernel<<<BT / 256, 256, 0, stream>>>(
        x, w1 + l * 4 * Cc * Cc, w2 + l * Cc * 4 * Cc,
        ln2g + l * Cc, ln2b + l * Cc);
  }
  head_kernel<<<BT / 16, 256, 0, stream>>>(x, tok, lnfg, lnfb, out);
}

// Round 2
// 306.653 us; speedup vs baseline: 2.1591x; 2.1591x over previous
//
#include <hip/hip_runtime.h>
#include <math.h>

// Problem constants (MicroGPT)
constexpr int Bc  = 16;
constexpr int Tc  = 2048;
constexpr int Cc  = 16;
constexpr int Hc  = 2;
constexpr int HSc = 8;
constexpr int Lc  = 2;
constexpr int Vc  = 256;
constexpr int BT  = Bc * Tc;          // 32768 tokens
constexpr float EPSc = 1e-5f;

// Attention v2 tiling: K-split for occupancy
constexpr int KC  = 128;              // keys per chunk (LDS tile)
constexpr int NCH = Tc / KC;          // 16 chunks
constexpr int QB  = 512;              // queries per block (256 thr x 2 ILP)
constexpr int NQB = Tc / QB;          // 4 query blocks per (b,h)

// ---------------------------------------------------------------------------
// LN helper: 16-wide layernorm entirely in registers
// ---------------------------------------------------------------------------
__device__ inline void layernorm16(const float* xr, float* h,
                                   const float* g, const float* b) {
  float m = 0.f;
#pragma unroll
  for (int c = 0; c < Cc; c++) m += xr[c];
  m *= (1.f / Cc);
  float var = 0.f;
#pragma unroll
  for (int c = 0; c < Cc; c++) { float d = xr[c] - m; var += d * d; }
  var *= (1.f / Cc);
  float rs = rsqrtf(var + EPSc);
#pragma unroll
  for (int c = 0; c < Cc; c++) h[c] = (xr[c] - m) * rs * g[c] + b[c];
}

// qkv from h (weights in LDS), store to q/k/v [B][H][T][HS]
__device__ inline void qkv_store(const float* h, const float* swq,
                                 const float* swk, const float* swv,
                                 int bb, int tt, float* __restrict__ q,
                                 float* __restrict__ k, float* __restrict__ v) {
#pragma unroll
  for (int hh = 0; hh < Hc; hh++) {
    float oq[HSc], ok[HSc], ov[HSc];
#pragma unroll
    for (int s = 0; s < HSc; s++) { oq[s] = 0.f; ok[s] = 0.f; ov[s] = 0.f; }
#pragma unroll
    for (int c = 0; c < Cc; c++) {
      float hv = h[c];
      const float* wqp = swq + (hh * Cc + c) * HSc;
      const float* wkp = swk + (hh * Cc + c) * HSc;
      const float* wvp = swv + (hh * Cc + c) * HSc;
#pragma unroll
      for (int s = 0; s < HSc; s++) {
        oq[s] += hv * wqp[s];
        ok[s] += hv * wkp[s];
        ov[s] += hv * wvp[s];
      }
    }
    long base = ((long)(bb * Hc + hh) * Tc + tt) * HSc;
    ((float4*)(q + base))[0] = make_float4(oq[0], oq[1], oq[2], oq[3]);
    ((float4*)(q + base))[1] = make_float4(oq[4], oq[5], oq[6], oq[7]);
    ((float4*)(k + base))[0] = make_float4(ok[0], ok[1], ok[2], ok[3]);
    ((float4*)(k + base))[1] = make_float4(ok[4], ok[5], ok[6], ok[7]);
    ((float4*)(v + base))[0] = make_float4(ov[0], ov[1], ov[2], ov[3]);
    ((float4*)(v + base))[1] = make_float4(ov[4], ov[5], ov[6], ov[7]);
  }
}

// ---------------------------------------------------------------------------
// K1) x = tok_emb[idx] + pos_emb ; h = LN1(x) ; q,k,v = h @ W  (layer 0)
// ---------------------------------------------------------------------------
__global__ __launch_bounds__(256) void embed_ln_qkv_kernel(
    const int* __restrict__ idx, const float* __restrict__ tok,
    const float* __restrict__ pos,
    const float* __restrict__ wq, const float* __restrict__ wk,
    const float* __restrict__ wv,
    const float* __restrict__ g, const float* __restrict__ b,
    float* __restrict__ x, float* __restrict__ q, float* __restrict__ k,
    float* __restrict__ v) {
  __shared__ float swq[Hc * Cc * HSc], swk[Hc * Cc * HSc], swv[Hc * Cc * HSc];
  __shared__ float sg[Cc], sb[Cc];
  int tid = threadIdx.x;
  swq[tid] = wq[tid];
  swk[tid] = wk[tid];
  swv[tid] = wv[tid];
  if (tid < Cc) { sg[tid] = g[tid]; sb[tid] = b[tid]; }
  __syncthreads();

  int tk = blockIdx.x * 256 + tid;
  int tt = tk & (Tc - 1);
  int bb = tk >> 11;
  int id = idx[tk];
  float xr[Cc];
  const float4* te = (const float4*)(tok + id * Cc);
  const float4* pe = (const float4*)(pos + tt * Cc);
  float4* xo = (float4*)(x + (long)tk * Cc);
#pragma unroll
  for (int i = 0; i < 4; i++) {
    float4 a = te[i], p = pe[i];
    float4 r = make_float4(a.x + p.x, a.y + p.y, a.z + p.z, a.w + p.w);
    xo[i] = r;
    xr[4*i] = r.x; xr[4*i+1] = r.y; xr[4*i+2] = r.z; xr[4*i+3] = r.w;
  }
  float h[Cc];
  layernorm16(xr, h, sg, sb);
  qkv_store(h, swq, swk, swv, bb, tt, q, k, v);
}

// ---------------------------------------------------------------------------
// K2) Causal flash attention with K-chunk split.  Each block: one (b,h),
//     one 512-query range (2 queries/thread), one 128-key chunk in LDS.
//     Writes UNNORMALIZED partials (acc[8], l) per (query, chunk).
//     No max subtraction (|score| << 1 -> exp safe; softmax shift-invariant).
// ---------------------------------------------------------------------------
__global__ __launch_bounds__(256) void attn_kernel(
    const float* __restrict__ q, const float* __restrict__ k,
    const float* __restrict__ v, float* __restrict__ pacc,
    float* __restrict__ pl) {
  int bh = blockIdx.x;            // 0..31
  int ch = blockIdx.y;            // 0..15
  int qb = blockIdx.z;            // 0..3
  int k0 = ch * KC;
  if (k0 >= (qb + 1) * QB) return;       // chunk entirely in causal future

  __shared__ float sk[KC * HSc], sv[KC * HSc];
  int tid = threadIdx.x;
  {
    const float4* ksrc = (const float4*)(k + ((long)bh * Tc + k0) * HSc);
    const float4* vsrc = (const float4*)(v + ((long)bh * Tc + k0) * HSc);
    ((float4*)sk)[tid] = ksrc[tid];      // KC*HSc/4 == 256 == blockDim
    ((float4*)sv)[tid] = vsrc[tid];
  }
  __syncthreads();

  int q1 = qb * QB + tid;         // position within T
  int q2 = q1 + 256;
  int kmax1 = q1 + 1 - k0; if (kmax1 > KC) kmax1 = KC;
  int kmax2 = q2 + 1 - k0; if (kmax2 > KC) kmax2 = KC;
  if (kmax2 <= 0) return;

  const float scale = 0.3535533905932738f;   // 8^-0.5
  float qr1[HSc], qr2[HSc];
  {
    const float4* qp1 = (const float4*)(q + ((long)bh * Tc + q1) * HSc);
    const float4* qp2 = (const float4*)(q + ((long)bh * Tc + q2) * HSc);
    float4 a = qp1[0], b = qp1[1], c = qp2[0], d = qp2[1];
    qr1[0]=a.x; qr1[1]=a.y; qr1[2]=a.z; qr1[3]=a.w;
    qr1[4]=b.x; qr1[5]=b.y; qr1[6]=b.z; qr1[7]=b.w;
    qr2[0]=c.x; qr2[1]=c.y; qr2[2]=c.z; qr2[3]=c.w;
    qr2[4]=d.x; qr2[5]=d.y; qr2[6]=d.z; qr2[7]=d.w;
#pragma unroll
    for (int i = 0; i < HSc; i++) { qr1[i] *= scale; qr2[i] *= scale; }
  }

  float l1 = 0.f, l2 = 0.f;
  float acc1[HSc] = {0,0,0,0,0,0,0,0};
  float acc2[HSc] = {0,0,0,0,0,0,0,0};

  for (int u = 0; u < kmax2; u++) {
    const float4* kr = (const float4*)(sk + u * HSc);
    float4 ka = kr[0], kb4 = kr[1];
    float s1 = qr1[0]*ka.x + qr1[1]*ka.y + qr1[2]*ka.z + qr1[3]*ka.w
             + qr1[4]*kb4.x + qr1[5]*kb4.y + qr1[6]*kb4.z + qr1[7]*kb4.w;
    float s2 = qr2[0]*ka.x + qr2[1]*ka.y + qr2[2]*ka.z + qr2[3]*ka.w
             + qr2[4]*kb4.x + qr2[5]*kb4.y + qr2[6]*kb4.z + qr2[7]*kb4.w;
    float p1 = __expf(s1);
    float p2 = __expf(s2);
    p1 = (u < kmax1) ? p1 : 0.f;
    l1 += p1; l2 += p2;
    const float4* vr = (const float4*)(sv + u * HSc);
    float4 va = vr[0], vb4 = vr[1];
    acc1[0] += p1*va.x;  acc1[1] += p1*va.y;
    acc1[2] += p1*va.z;  acc1[3] += p1*va.w;
    acc1[4] += p1*vb4.x; acc1[5] += p1*vb4.y;
    acc1[6] += p1*vb4.z; acc1[7] += p1*vb4.w;
    acc2[0] += p2*va.x;  acc2[1] += p2*va.y;
    acc2[2] += p2*va.z;  acc2[3] += p2*va.w;
    acc2[4] += p2*vb4.x; acc2[5] += p2*vb4.y;
    acc2[6] += p2*vb4.z; acc2[7] += p2*vb4.w;
  }

  long rec = (long)(bh * NCH + ch) * Tc;
  if (kmax1 > 0) {
    float4* pa = (float4*)(pacc + (rec + q1) * 8);
    pa[0] = make_float4(acc1[0], acc1[1], acc1[2], acc1[3]);
    pa[1] = make_float4(acc1[4], acc1[5], acc1[6], acc1[7]);
    pl[rec + q1] = l1;
  }
  {
    float4* pa = (float4*)(pacc + (rec + q2) * 8);
    pa[0] = make_float4(acc2[0], acc2[1], acc2[2], acc2[3]);
    pa[1] = make_float4(acc2[4], acc2[5], acc2[6], acc2[7]);
    pl[rec + q2] = l2;
  }
}

// ---------------------------------------------------------------------------
// Shared tail: reduce partials -> o ; x += o @ wo^T ; x += MLP(LN2(x))
// Returns updated xr.
// ---------------------------------------------------------------------------
__device__ inline void reduce_proj_mlp(
    const float* __restrict__ pacc, const float* __restrict__ pl,
    const float* swo, const float* sw1, const float* sw2,
    const float* sg2, const float* sb2, int bb, int tt, float* xr) {
  // --- reduce partials over chunks -> orow[16]
  float orow[Cc];
  int nch = tt / KC + 1;
#pragma unroll
  for (int hh = 0; hh < Hc; hh++) {
    int bh = bb * Hc + hh;
    float o8[HSc] = {0,0,0,0,0,0,0,0};
    float l = 0.f;
    for (int ch = 0; ch < nch; ch++) {
      long rec = (long)(bh * NCH + ch) * Tc + tt;
      const float4* pa = (const float4*)(pacc + rec * 8);
      float4 a = pa[0], b = pa[1];
      o8[0]+=a.x; o8[1]+=a.y; o8[2]+=a.z; o8[3]+=a.w;
      o8[4]+=b.x; o8[5]+=b.y; o8[6]+=b.z; o8[7]+=b.w;
      l += pl[rec];
    }
    float inv = 1.f / l;
#pragma unroll
    for (int s = 0; s < HSc; s++) orow[hh * HSc + s] = o8[s] * inv;
  }
  // --- proj: x += o @ wo^T
#pragma unroll
  for (int c = 0; c < Cc; c++) {
    float acc = 0.f;
#pragma unroll
    for (int kk = 0; kk < Cc; kk++) acc += orow[kk] * swo[c * Cc + kk];
    xr[c] += acc;
  }
  // --- mlp
  float h[Cc];
  layernorm16(xr, h, sg2, sb2);
  float r[Cc];
#pragma unroll
  for (int c = 0; c < Cc; c++) r[c] = 0.f;
  for (int j = 0; j < 4 * Cc; j++) {
    float acc = 0.f;
#pragma unroll
    for (int c = 0; c < Cc; c++) acc += h[c] * sw1[j * Cc + c];
    acc = fmaxf(acc, 0.f);
#pragma unroll
    for (int c = 0; c < Cc; c++) r[c] += acc * sw2[c * 4 * Cc + j];
  }
#pragma unroll
  for (int c = 0; c < Cc; c++) xr[c] += r[c];
}

// ---------------------------------------------------------------------------
// K3) layer-l epilogue + layer-(l+1) LN1+QKV, fused per token
// ---------------------------------------------------------------------------
__global__ __launch_bounds__(256) void red_proj_mlp_qkv_kernel(
    const float* __restrict__ pacc, const float* __restrict__ pl,
    const float* __restrict__ wo, const float* __restrict__ g2,
    const float* __restrict__ b2, const float* __restrict__ w1,
    const float* __restrict__ w2,
    const float* __restrict__ wq, const float* __restrict__ wk,
    const float* __restrict__ wv, const float* __restrict__ g1,
    const float* __restrict__ b1,
    float* __restrict__ x, float* __restrict__ q, float* __restrict__ k,
    float* __restrict__ v) {
  __shared__ float swo[Cc * Cc], sw1[4 * Cc * Cc], sw2[Cc * 4 * Cc];
  __shared__ float swq[256], swk[256], swv[256];
  __shared__ float sg2[Cc], sb2[Cc], sg1[Cc], sb1[Cc];
  int tid = threadIdx.x;
  swo[tid] = wo[tid];
  swq[tid] = wq[tid]; swk[tid] = wk[tid]; swv[tid] = wv[tid];
#pragma unroll
  for (int i = 0; i < 4; i++) {
    sw1[tid + i * 256] = w1[tid + i * 256];
    sw2[tid + i * 256] = w2[tid + i * 256];
  }
  if (tid < Cc) {
    sg2[tid] = g2[tid]; sb2[tid] = b2[tid];
    sg1[tid] = g1[tid]; sb1[tid] = b1[tid];
  }
  __syncthreads();

  int tk = blockIdx.x * 256 + tid;
  int bb = tk >> 11, tt = tk & (Tc - 1);
  float xr[Cc];
  float4* xp = (float4*)(x + (long)tk * Cc);
#pragma unroll
  for (int i = 0; i < 4; i++) {
    float4 a = xp[i];
    xr[4*i]=a.x; xr[4*i+1]=a.y; xr[4*i+2]=a.z; xr[4*i+3]=a.w;
  }
  reduce_proj_mlp(pacc, pl, swo, sw1, sw2, sg2, sb2, bb, tt, xr);
#pragma unroll
  for (int i = 0; i < 4; i++)
    xp[i] = make_float4(xr[4*i], xr[4*i+1], xr[4*i+2], xr[4*i+3]);

  float h[Cc];
  layernorm16(xr, h, sg1, sb1);
  qkv_store(h, swq, swk, swv, bb, tt, q, k, v);
}

// ---------------------------------------------------------------------------
// K5) final-layer epilogue + LNf -> hf  (2 MB)
// ---------------------------------------------------------------------------
__global__ __launch_bounds__(256) void red_proj_mlp_lnf_kernel(
    const float* __restrict__ pacc, const float* __restrict__ pl,
    const float* __restrict__ wo, const float* __restrict__ g2,
    const float* __restrict__ b2, const float* __restrict__ w1,
    const float* __restrict__ w2, const float* __restrict__ gf,
    const float* __restrict__ bf,
    const float* __restrict__ x, float* __restrict__ hf) {
  __shared__ float swo[Cc * Cc], sw1[4 * Cc * Cc], sw2[Cc * 4 * Cc];
  __shared__ float sg2[Cc], sb2[Cc], sgf[Cc], sbf[Cc];
  int tid = threadIdx.x;
  swo[tid] = wo[tid];
#pragma unroll
  for (int i = 0; i < 4; i++) {
    sw1[tid + i * 256] = w1[tid + i * 256];
    sw2[tid + i * 256] = w2[tid + i * 256];
  }
  if (tid < Cc) {
    sg2[tid] = g2[tid]; sb2[tid] = b2[tid];
    sgf[tid] = gf[tid]; sbf[tid] = bf[tid];
  }
  __syncthreads();

  int tk = blockIdx.x * 256 + tid;
  int bb = tk >> 11, tt = tk & (Tc - 1);
  float xr[Cc];
  const float4* xp = (const float4*)(x + (long)tk * Cc);
#pragma unroll
  for (int i = 0; i < 4; i++) {
    float4 a = xp[i];
    xr[4*i]=a.x; xr[4*i+1]=a.y; xr[4*i+2]=a.z; xr[4*i+3]=a.w;
  }
  reduce_proj_mlp(pacc, pl, swo, sw1, sw2, sg2, sb2, bb, tt, xr);
  float h[Cc];
  layernorm16(xr, h, sgf, sbf);
  float4* hp = (float4*)(hf + (long)tk * Cc);
#pragma unroll
  for (int i = 0; i < 4; i++)
    hp[i] = make_float4(h[4*i], h[4*i+1], h[4*i+2], h[4*i+3]);
}

// ---------------------------------------------------------------------------
// K6) out = hf @ tok_emb^T   (16 rows per block; tok_emb^T in LDS)
// ---------------------------------------------------------------------------
__global__ __launch_bounds__(256) void head_kernel(
    const float* __restrict__ hf, const float* __restrict__ tok,
    float* __restrict__ out) {
  __shared__ float sembT[Cc * Vc];   // [c][v], conflict-free
  __shared__ float4 sh4[16][4];
  int tid = threadIdx.x;             // vocab id
  const float4* ep = (const float4*)(tok + tid * Cc);
#pragma unroll
  for (int i = 0; i < 4; i++) {
    float4 a = ep[i];
    sembT[(4*i+0) * Vc + tid] = a.x;
    sembT[(4*i+1) * Vc + tid] = a.y;
    sembT[(4*i+2) * Vc + tid] = a.z;
    sembT[(4*i+3) * Vc + tid] = a.w;
  }
  int row0 = blockIdx.x * 16;
  if (tid < 64)
    ((float4*)sh4)[tid] = ((const float4*)(hf + (long)row0 * Cc))[tid];
  __syncthreads();

  float e[Cc];
#pragma unroll
  for (int c = 0; c < Cc; c++) e[c] = sembT[c * Vc + tid];
#pragma unroll
  for (int r = 0; r < 16; r++) {
    float4 h0 = sh4[r][0], h1 = sh4[r][1], h2 = sh4[r][2], h3 = sh4[r][3];
    float acc = h0.x*e[0] + h0.y*e[1] + h0.z*e[2] + h0.w*e[3]
              + h1.x*e[4] + h1.y*e[5] + h1.z*e[6] + h1.w*e[7]
              + h2.x*e[8] + h2.y*e[9] + h2.z*e[10]+ h2.w*e[11]
              + h3.x*e[12]+ h3.y*e[13]+ h3.z*e[14]+ h3.w*e[15];
    out[(long)(row0 + r) * Vc + tid] = acc;
  }
}

// ---------------------------------------------------------------------------
// launcher
// ---------------------------------------------------------------------------
extern "C" void kernel_launch(void* const* d_in, const int* in_sizes, int n_in,
                              void* d_out, int out_size, void* d_ws,
                              size_t ws_size, hipStream_t stream) {
  const int*   idx  = (const int*)  d_in[0];
  const float* tok  = (const float*)d_in[1];
  const float* pos  = (const float*)d_in[2];
  const float* wq   = (const float*)d_in[3];
  const float* wk   = (const float*)d_in[4];
  const float* wv   = (const float*)d_in[5];
  const float* wo   = (const float*)d_in[6];
  const float* ln1g = (const float*)d_in[7];
  const float* ln1b = (const float*)d_in[8];
  const float* ln2g = (const float*)d_in[9];
  const float* ln2b = (const float*)d_in[10];
  const float* w1   = (const float*)d_in[11];
  const float* w2   = (const float*)d_in[12];
  const float* lnfg = (const float*)d_in[13];
  const float* lnfb = (const float*)d_in[14];
  float* out = (float*)d_out;

  // workspace layout (floats):
  // x: 2MB | q,k,v: 2MB each | pacc: 33.5MB | pl: 4MB  -> ~45.5MB total
  float* x    = (float*)d_ws;
  float* q    = x + (long)BT * Cc;
  float* k    = q + (long)Bc * Hc * Tc * HSc;
  float* v    = k + (long)Bc * Hc * Tc * HSc;
  float* pacc = v + (long)Bc * Hc * Tc * HSc;
  float* pl   = pacc + (long)Bc * Hc * NCH * Tc * HSc;
  float* hf   = q;   // reuse q after last attention

  dim3 agrid(Bc * Hc, NCH, NQB);

  embed_ln_qkv_kernel<<<BT / 256, 256, 0, stream>>>(
      idx, tok, pos, wq, wk, wv, ln1g, ln1b, x, q, k, v);
  attn_kernel<<<agrid, 256, 0, stream>>>(q, k, v, pacc, pl);
  red_proj_mlp_qkv_kernel<<<BT / 256, 256, 0, stream>>>(
      pacc, pl, wo, ln2g, ln2b, w1, w2,
      wq + Hc * Cc * HSc, wk + Hc * Cc * HSc, wv + Hc * Cc * HSc,
      ln1g + Cc, ln1b + Cc, x, q, k, v);
  attn_kernel<<<agrid, 256, 0, stream>>>(q, k, v, pacc, pl);
  red_proj_mlp_lnf_kernel<<<BT / 256, 256, 0, stream>>>(
      pacc, pl, wo + Cc * Cc, ln2g + Cc, ln2b + Cc,
      w1 + 4 * Cc * Cc, w2 + 4 * Cc * Cc, lnfg, lnfb, x, hf);
  head_kernel<<<BT / 16, 256, 0, stream>>>(hf, tok, out);
}

// Round 3
// 266.690 us; speedup vs baseline: 2.4827x; 1.1498x over previous
//
#include <hip/hip_runtime.h>
#include <math.h>

// Problem constants (MicroGPT)
constexpr int Bc  = 16;
constexpr int Tc  = 2048;
constexpr int Cc  = 16;
constexpr int Hc  = 2;
constexpr int HSc = 8;
constexpr int Lc  = 2;
constexpr int Vc  = 256;
constexpr int BT  = Bc * Tc;          // 32768 tokens
constexpr float EPSc = 1e-5f;

// Attention tiling: K-chunk split + 4 queries/thread
constexpr int KC  = 128;              // keys per chunk (LDS tile)
constexpr int NCH = Tc / KC;          // 16 chunks
constexpr int QB  = 1024;             // queries per block (256 thr x 4 ILP)
constexpr int NQB = Tc / QB;          // 2 query blocks per (b,h)

typedef float f2 __attribute__((ext_vector_type(2)));

// ---------------------------------------------------------------------------
// LN helper: 16-wide layernorm entirely in registers
// ---------------------------------------------------------------------------
__device__ inline void layernorm16(const float* xr, float* h,
                                   const float* g, const float* b) {
  float m = 0.f;
#pragma unroll
  for (int c = 0; c < Cc; c++) m += xr[c];
  m *= (1.f / Cc);
  float var = 0.f;
#pragma unroll
  for (int c = 0; c < Cc; c++) { float d = xr[c] - m; var += d * d; }
  var *= (1.f / Cc);
  float rs = rsqrtf(var + EPSc);
#pragma unroll
  for (int c = 0; c < Cc; c++) h[c] = (xr[c] - m) * rs * g[c] + b[c];
}

// qkv from h (weights in LDS), store to q/k/v [B][H][T][HS]
__device__ inline void qkv_store(const float* h, const float* swq,
                                 const float* swk, const float* swv,
                                 int bb, int tt, float* __restrict__ q,
                                 float* __restrict__ k, float* __restrict__ v) {
#pragma unroll
  for (int hh = 0; hh < Hc; hh++) {
    float oq[HSc], ok[HSc], ov[HSc];
#pragma unroll
    for (int s = 0; s < HSc; s++) { oq[s] = 0.f; ok[s] = 0.f; ov[s] = 0.f; }
#pragma unroll
    for (int c = 0; c < Cc; c++) {
      float hv = h[c];
      const float* wqp = swq + (hh * Cc + c) * HSc;
      const float* wkp = swk + (hh * Cc + c) * HSc;
      const float* wvp = swv + (hh * Cc + c) * HSc;
#pragma unroll
      for (int s = 0; s < HSc; s++) {
        oq[s] += hv * wqp[s];
        ok[s] += hv * wkp[s];
        ov[s] += hv * wvp[s];
      }
    }
    long base = ((long)(bb * Hc + hh) * Tc + tt) * HSc;
    ((float4*)(q + base))[0] = make_float4(oq[0], oq[1], oq[2], oq[3]);
    ((float4*)(q + base))[1] = make_float4(oq[4], oq[5], oq[6], oq[7]);
    ((float4*)(k + base))[0] = make_float4(ok[0], ok[1], ok[2], ok[3]);
    ((float4*)(k + base))[1] = make_float4(ok[4], ok[5], ok[6], ok[7]);
    ((float4*)(v + base))[0] = make_float4(ov[0], ov[1], ov[2], ov[3]);
    ((float4*)(v + base))[1] = make_float4(ov[4], ov[5], ov[6], ov[7]);
  }
}

// ---------------------------------------------------------------------------
// K1) x = tok_emb[idx] + pos_emb ; h = LN1(x) ; q,k,v = h @ W  (layer 0)
//     64-thread blocks so all 256 CUs get work.
// ---------------------------------------------------------------------------
__global__ __launch_bounds__(64) void embed_ln_qkv_kernel(
    const int* __restrict__ idx, const float* __restrict__ tok,
    const float* __restrict__ pos,
    const float* __restrict__ wq, const float* __restrict__ wk,
    const float* __restrict__ wv,
    const float* __restrict__ g, const float* __restrict__ b,
    float* __restrict__ x, float* __restrict__ q, float* __restrict__ k,
    float* __restrict__ v) {
  __shared__ float swq[256], swk[256], swv[256];
  __shared__ float sg[Cc], sb[Cc];
  int tid = threadIdx.x;
  ((float4*)swq)[tid] = ((const float4*)wq)[tid];   // 64*4 == 256
  ((float4*)swk)[tid] = ((const float4*)wk)[tid];
  ((float4*)swv)[tid] = ((const float4*)wv)[tid];
  if (tid < Cc) { sg[tid] = g[tid]; sb[tid] = b[tid]; }
  __syncthreads();

  int tk = blockIdx.x * 64 + tid;
  int tt = tk & (Tc - 1);
  int bb = tk >> 11;
  int id = idx[tk];
  float xr[Cc];
  const float4* te = (const float4*)(tok + id * Cc);
  const float4* pe = (const float4*)(pos + tt * Cc);
  float4* xo = (float4*)(x + (long)tk * Cc);
#pragma unroll
  for (int i = 0; i < 4; i++) {
    float4 a = te[i], p = pe[i];
    float4 r = make_float4(a.x + p.x, a.y + p.y, a.z + p.z, a.w + p.w);
    xo[i] = r;
    xr[4*i] = r.x; xr[4*i+1] = r.y; xr[4*i+2] = r.z; xr[4*i+3] = r.w;
  }
  float h[Cc];
  layernorm16(xr, h, sg, sb);
  qkv_store(h, swq, swk, swv, bb, tt, q, k, v);
}

// ---------------------------------------------------------------------------
// K2) Causal flash attention, K-chunk split, 4 queries/thread, packed f32.
//     Writes UNNORMALIZED partials (acc[8], l) per (query, chunk).
//     No max subtraction (|score| << 1 -> exp safe; softmax shift-invariant).
//     q pre-scaled by log2(e)*HS^-0.5 so p = exp2(s) is a single v_exp_f32.
// ---------------------------------------------------------------------------
__global__ __launch_bounds__(256) void attn_kernel(
    const float* __restrict__ q, const float* __restrict__ k,
    const float* __restrict__ v, float* __restrict__ pacc,
    float* __restrict__ pl) {
  int bh = blockIdx.x;            // 0..31
  int ch = blockIdx.y;            // 0..15
  int qb = blockIdx.z;            // 0..1
  int k0 = ch * KC;
  if (k0 >= (qb + 1) * QB) return;       // chunk entirely in causal future

  __shared__ float sk[KC * HSc], sv[KC * HSc];
  int tid = threadIdx.x;
  {
    const float4* ksrc = (const float4*)(k + ((long)bh * Tc + k0) * HSc);
    const float4* vsrc = (const float4*)(v + ((long)bh * Tc + k0) * HSc);
    ((float4*)sk)[tid] = ksrc[tid];      // KC*HSc/4 == 256 == blockDim
    ((float4*)sv)[tid] = vsrc[tid];
  }
  __syncthreads();

  const float pre = 0.35355339059327373f * 1.4426950408889634f;
  int q0 = qb * QB + tid;         // queries q0 + 256*i
  f2 qr[4][4];
  f2 acc[4][4];
  float l[4] = {0.f, 0.f, 0.f, 0.f};
  int kmax[4];
#pragma unroll
  for (int i = 0; i < 4; i++) {
    int qi = q0 + 256 * i;
    const f2* qp = (const f2*)(q + ((long)bh * Tc + qi) * HSc);
#pragma unroll
    for (int j = 0; j < 4; j++) {
      qr[i][j] = qp[j] * pre;
      acc[i][j] = {0.f, 0.f};
    }
    int km = qi + 1 - k0;
    kmax[i] = km < 0 ? 0 : (km > KC ? KC : km);
  }

  const f2* skp = (const f2*)sk;
  const f2* svp = (const f2*)sv;

#define ATTN_STEP(u, MASKED)                                              \
  {                                                                       \
    f2 k0v = skp[(u)*4+0], k1v = skp[(u)*4+1],                            \
       k2v = skp[(u)*4+2], k3v = skp[(u)*4+3];                            \
    f2 v0v = svp[(u)*4+0], v1v = svp[(u)*4+1],                            \
       v2v = svp[(u)*4+2], v3v = svp[(u)*4+3];                            \
    _Pragma("unroll")                                                     \
    for (int i = 0; i < 4; i++) {                                         \
      f2 d = qr[i][0] * k0v;                                              \
      d += qr[i][1] * k1v;                                                \
      d += qr[i][2] * k2v;                                                \
      d += qr[i][3] * k3v;                                                \
      float s = d.x + d.y;                                                \
      float p = __builtin_amdgcn_exp2f(s);                                \
      if (MASKED) p = ((u) < kmax[i]) ? p : 0.f;                          \
      l[i] += p;                                                          \
      acc[i][0] += p * v0v;                                               \
      acc[i][1] += p * v1v;                                               \
      acc[i][2] += p * v2v;                                               \
      acc[i][3] += p * v3v;                                               \
    }                                                                     \
  }

  bool full = (k0 + KC) <= qb * QB;   // all 4 queries see every key in chunk
  if (full) {
    for (int u = 0; u < KC; u++) ATTN_STEP(u, false)
  } else {
    int bound = kmax[3];
    for (int u = 0; u < bound; u++) ATTN_STEP(u, true)
  }
#undef ATTN_STEP

  long rec = (long)(bh * NCH + ch) * Tc;
#pragma unroll
  for (int i = 0; i < 4; i++) {
    if (kmax[i] > 0) {
      int qi = q0 + 256 * i;
      float4* pa = (float4*)(pacc + (rec + qi) * 8);
      pa[0] = make_float4(acc[i][0].x, acc[i][0].y, acc[i][1].x, acc[i][1].y);
      pa[1] = make_float4(acc[i][2].x, acc[i][2].y, acc[i][3].x, acc[i][3].y);
      pl[rec + qi] = l[i];
    }
  }
}

// ---------------------------------------------------------------------------
// Shared tail: reduce partials -> o ; x += o @ wo^T ; x += MLP(LN2(x))
// ---------------------------------------------------------------------------
__device__ inline void reduce_proj_mlp(
    const float* __restrict__ pacc, const float* __restrict__ pl,
    const float* swo, const float* sw1, const float* sw2,
    const float* sg2, const float* sb2, int bb, int tt, float* xr) {
  float orow[Cc];
  int nch = tt / KC + 1;
#pragma unroll
  for (int hh = 0; hh < Hc; hh++) {
    int bh = bb * Hc + hh;
    float o8[HSc] = {0,0,0,0,0,0,0,0};
    float l = 0.f;
    for (int ch = 0; ch < nch; ch++) {
      long rec = (long)(bh * NCH + ch) * Tc + tt;
      const float4* pa = (const float4*)(pacc + rec * 8);
      float4 a = pa[0], b = pa[1];
      o8[0]+=a.x; o8[1]+=a.y; o8[2]+=a.z; o8[3]+=a.w;
      o8[4]+=b.x; o8[5]+=b.y; o8[6]+=b.z; o8[7]+=b.w;
      l += pl[rec];
    }
    float inv = 1.f / l;
#pragma unroll
    for (int s = 0; s < HSc; s++) orow[hh * HSc + s] = o8[s] * inv;
  }
#pragma unroll
  for (int c = 0; c < Cc; c++) {
    float acc = 0.f;
#pragma unroll
    for (int kk = 0; kk < Cc; kk++) acc += orow[kk] * swo[c * Cc + kk];
    xr[c] += acc;
  }
  float h[Cc];
  layernorm16(xr, h, sg2, sb2);
  float r[Cc];
#pragma unroll
  for (int c = 0; c < Cc; c++) r[c] = 0.f;
  for (int j = 0; j < 4 * Cc; j++) {
    float acc = 0.f;
#pragma unroll
    for (int c = 0; c < Cc; c++) acc += h[c] * sw1[j * Cc + c];
    acc = fmaxf(acc, 0.f);
#pragma unroll
    for (int c = 0; c < Cc; c++) r[c] += acc * sw2[c * 4 * Cc + j];
  }
#pragma unroll
  for (int c = 0; c < Cc; c++) xr[c] += r[c];
}

// ---------------------------------------------------------------------------
// K3) layer-l epilogue + layer-(l+1) LN1+QKV, fused per token (64-thr blocks)
// ---------------------------------------------------------------------------
__global__ __launch_bounds__(64) void red_proj_mlp_qkv_kernel(
    const float* __restrict__ pacc, const float* __restrict__ pl,
    const float* __restrict__ wo, const float* __restrict__ g2,
    const float* __restrict__ b2, const float* __restrict__ w1,
    const float* __restrict__ w2,
    const float* __restrict__ wq, const float* __restrict__ wk,
    const float* __restrict__ wv, const float* __restrict__ g1,
    const float* __restrict__ b1,
    float* __restrict__ x, float* __restrict__ q, float* __restrict__ k,
    float* __restrict__ v) {
  __shared__ float swo[256], sw1[1024], sw2[1024];
  __shared__ float swq[256], swk[256], swv[256];
  __shared__ float sg2[Cc], sb2[Cc], sg1[Cc], sb1[Cc];
  int tid = threadIdx.x;
  ((float4*)swo)[tid] = ((const float4*)wo)[tid];
  ((float4*)swq)[tid] = ((const float4*)wq)[tid];
  ((float4*)swk)[tid] = ((const float4*)wk)[tid];
  ((float4*)swv)[tid] = ((const float4*)wv)[tid];
#pragma unroll
  for (int i = 0; i < 4; i++) {
    ((float4*)sw1)[tid + 64*i] = ((const float4*)w1)[tid + 64*i];
    ((float4*)sw2)[tid + 64*i] = ((const float4*)w2)[tid + 64*i];
  }
  if (tid < Cc) {
    sg2[tid] = g2[tid]; sb2[tid] = b2[tid];
    sg1[tid] = g1[tid]; sb1[tid] = b1[tid];
  }
  __syncthreads();

  int tk = blockIdx.x * 64 + tid;
  int bb = tk >> 11, tt = tk & (Tc - 1);
  float xr[Cc];
  float4* xp = (float4*)(x + (long)tk * Cc);
#pragma unroll
  for (int i = 0; i < 4; i++) {
    float4 a = xp[i];
    xr[4*i]=a.x; xr[4*i+1]=a.y; xr[4*i+2]=a.z; xr[4*i+3]=a.w;
  }
  reduce_proj_mlp(pacc, pl, swo, sw1, sw2, sg2, sb2, bb, tt, xr);
#pragma unroll
  for (int i = 0; i < 4; i++)
    xp[i] = make_float4(xr[4*i], xr[4*i+1], xr[4*i+2], xr[4*i+3]);

  float h[Cc];
  layernorm16(xr, h, sg1, sb1);
  qkv_store(h, swq, swk, swv, bb, tt, q, k, v);
}

// ---------------------------------------------------------------------------
// K5) final-layer epilogue + LNf -> hf  (64-thr blocks)
// ---------------------------------------------------------------------------
__global__ __launch_bounds__(64) void red_proj_mlp_lnf_kernel(
    const float* __restrict__ pacc, const float* __restrict__ pl,
    const float* __restrict__ wo, const float* __restrict__ g2,
    const float* __restrict__ b2, const float* __restrict__ w1,
    const float* __restrict__ w2, const float* __restrict__ gf,
    const float* __restrict__ bf,
    const float* __restrict__ x, float* __restrict__ hf) {
  __shared__ float swo[256], sw1[1024], sw2[1024];
  __shared__ float sg2[Cc], sb2[Cc], sgf[Cc], sbf[Cc];
  int tid = threadIdx.x;
  ((float4*)swo)[tid] = ((const float4*)wo)[tid];
#pragma unroll
  for (int i = 0; i < 4; i++) {
    ((float4*)sw1)[tid + 64*i] = ((const float4*)w1)[tid + 64*i];
    ((float4*)sw2)[tid + 64*i] = ((const float4*)w2)[tid + 64*i];
  }
  if (tid < Cc) {
    sg2[tid] = g2[tid]; sb2[tid] = b2[tid];
    sgf[tid] = gf[tid]; sbf[tid] = bf[tid];
  }
  __syncthreads();

  int tk = blockIdx.x * 64 + tid;
  int bb = tk >> 11, tt = tk & (Tc - 1);
  float xr[Cc];
  const float4* xp = (const float4*)(x + (long)tk * Cc);
#pragma unroll
  for (int i = 0; i < 4; i++) {
    float4 a = xp[i];
    xr[4*i]=a.x; xr[4*i+1]=a.y; xr[4*i+2]=a.z; xr[4*i+3]=a.w;
  }
  reduce_proj_mlp(pacc, pl, swo, sw1, sw2, sg2, sb2, bb, tt, xr);
  float h[Cc];
  layernorm16(xr, h, sgf, sbf);
  float4* hp = (float4*)(hf + (long)tk * Cc);
#pragma unroll
  for (int i = 0; i < 4; i++)
    hp[i] = make_float4(h[4*i], h[4*i+1], h[4*i+2], h[4*i+3]);
}

// ---------------------------------------------------------------------------
// K6) out = hf @ tok_emb^T   (16 rows per block; tok_emb^T in LDS)
// ---------------------------------------------------------------------------
__global__ __launch_bounds__(256) void head_kernel(
    const float* __restrict__ hf, const float* __restrict__ tok,
    float* __restrict__ out) {
  __shared__ float sembT[Cc * Vc];   // [c][v], conflict-free
  __shared__ float4 sh4[16][4];
  int tid = threadIdx.x;             // vocab id
  const float4* ep = (const float4*)(tok + tid * Cc);
#pragma unroll
  for (int i = 0; i < 4; i++) {
    float4 a = ep[i];
    sembT[(4*i+0) * Vc + tid] = a.x;
    sembT[(4*i+1) * Vc + tid] = a.y;
    sembT[(4*i+2) * Vc + tid] = a.z;
    sembT[(4*i+3) * Vc + tid] = a.w;
  }
  int row0 = blockIdx.x * 16;
  if (tid < 64)
    ((float4*)sh4)[tid] = ((const float4*)(hf + (long)row0 * Cc))[tid];
  __syncthreads();

  float e[Cc];
#pragma unroll
  for (int c = 0; c < Cc; c++) e[c] = sembT[c * Vc + tid];
#pragma unroll
  for (int r = 0; r < 16; r++) {
    float4 h0 = sh4[r][0], h1 = sh4[r][1], h2 = sh4[r][2], h3 = sh4[r][3];
    float acc = h0.x*e[0] + h0.y*e[1] + h0.z*e[2] + h0.w*e[3]
              + h1.x*e[4] + h1.y*e[5] + h1.z*e[6] + h1.w*e[7]
              + h2.x*e[8] + h2.y*e[9] + h2.z*e[10]+ h2.w*e[11]
              + h3.x*e[12]+ h3.y*e[13]+ h3.z*e[14]+ h3.w*e[15];
    out[(long)(row0 + r) * Vc + tid] = acc;
  }
}

// ---------------------------------------------------------------------------
// launcher
// ---------------------------------------------------------------------------
extern "C" void kernel_launch(void* const* d_in, const int* in_sizes, int n_in,
                              void* d_out, int out_size, void* d_ws,
                              size_t ws_size, hipStream_t stream) {
  const int*   idx  = (const int*)  d_in[0];
  const float* tok  = (const float*)d_in[1];
  const float* pos  = (const float*)d_in[2];
  const float* wq   = (const float*)d_in[3];
  const float* wk   = (const float*)d_in[4];
  const float* wv   = (const float*)d_in[5];
  const float* wo   = (const float*)d_in[6];
  const float* ln1g = (const float*)d_in[7];
  const float* ln1b = (const float*)d_in[8];
  const float* ln2g = (const float*)d_in[9];
  const float* ln2b = (const float*)d_in[10];
  const float* w1   = (const float*)d_in[11];
  const float* w2   = (const float*)d_in[12];
  const float* lnfg = (const float*)d_in[13];
  const float* lnfb = (const float*)d_in[14];
  float* out = (float*)d_out;

  // workspace layout (floats):
  // x: 2MB | q,k,v: 2MB each | pacc: 33.5MB | pl: 4MB  -> ~45.5MB total
  float* x    = (float*)d_ws;
  float* q    = x + (long)BT * Cc;
  float* k    = q + (long)Bc * Hc * Tc * HSc;
  float* v    = k + (long)Bc * Hc * Tc * HSc;
  float* pacc = v + (long)Bc * Hc * Tc * HSc;
  float* pl   = pacc + (long)Bc * Hc * NCH * Tc * HSc;
  float* hf   = q;   // reuse q after last attention

  dim3 agrid(Bc * Hc, NCH, NQB);

  embed_ln_qkv_kernel<<<BT / 64, 64, 0, stream>>>(
      idx, tok, pos, wq, wk, wv, ln1g, ln1b, x, q, k, v);
  attn_kernel<<<agrid, 256, 0, stream>>>(q, k, v, pacc, pl);
  red_proj_mlp_qkv_kernel<<<BT / 64, 64, 0, stream>>>(
      pacc, pl, wo, ln2g, ln2b, w1, w2,
      wq + Hc * Cc * HSc, wk + Hc * Cc * HSc, wv + Hc * Cc * HSc,
      ln1g + Cc, ln1b + Cc, x, q, k, v);
  attn_kernel<<<agrid, 256, 0, stream>>>(q, k, v, pacc, pl);
  red_proj_mlp_lnf_kernel<<<BT / 64, 64, 0, stream>>>(
      pacc, pl, wo + Cc * Cc, ln2g + Cc, ln2b + Cc,
      w1 + 4 * Cc * Cc, w2 + 4 * Cc * Cc, lnfg, lnfb, x, hf);
  head_kernel<<<BT / 16, 256, 0, stream>>>(hf, tok, out);
}

// Round 4
// 236.030 us; speedup vs baseline: 2.8052x; 1.1299x over previous
//
#include <hip/hip_runtime.h>
#include <math.h>

// Problem constants (MicroGPT)
constexpr int Bc  = 16;
constexpr int Tc  = 2048;
constexpr int Cc  = 16;
constexpr int Hc  = 2;
constexpr int HSc = 8;
constexpr int Lc  = 2;
constexpr int Vc  = 256;
constexpr int BT  = Bc * Tc;          // 32768 tokens
constexpr float EPSc = 1e-5f;

// Attention tiling: K-chunk split + 4 queries/thread
constexpr int KC  = 128;              // keys per chunk (LDS tile)
constexpr int NCH = Tc / KC;          // 16 chunks
constexpr int QB  = 1024;             // queries per block (256 thr x 4 ILP)
constexpr int NQB = Tc / QB;          // 2 query blocks per (b,h)

typedef float f2 __attribute__((ext_vector_type(2)));

__device__ inline float shx(float v, int m) { return __shfl_xor(v, m, 64); }

// ---------------------------------------------------------------------------
// LN helper: 16-wide layernorm entirely in registers
// ---------------------------------------------------------------------------
__device__ inline void layernorm16(const float* xr, float* h,
                                   const float* g, const float* b) {
  float m = 0.f;
#pragma unroll
  for (int c = 0; c < Cc; c++) m += xr[c];
  m *= (1.f / Cc);
  float var = 0.f;
#pragma unroll
  for (int c = 0; c < Cc; c++) { float d = xr[c] - m; var += d * d; }
  var *= (1.f / Cc);
  float rs = rsqrtf(var + EPSc);
#pragma unroll
  for (int c = 0; c < Cc; c++) h[c] = (xr[c] - m) * rs * g[c] + b[c];
}

// ---------------------------------------------------------------------------
// 4-lane-coop QKV: lane j computes s={2j,2j+1} of every (head, q/k/v) vector
// ---------------------------------------------------------------------------
__device__ inline void qkv_store_lane(const float* h, const float* swq,
                                      const float* swk, const float* swv,
                                      int bb, int tt, int j,
                                      float* __restrict__ q,
                                      float* __restrict__ k,
                                      float* __restrict__ v) {
#pragma unroll
  for (int hh = 0; hh < Hc; hh++) {
    float q0 = 0.f, q1 = 0.f, k0 = 0.f, k1 = 0.f, v0 = 0.f, v1 = 0.f;
#pragma unroll
    for (int c = 0; c < Cc; c++) {
      float hv = h[c];
      const float* wqp = swq + (hh * Cc + c) * HSc + 2 * j;
      const float* wkp = swk + (hh * Cc + c) * HSc + 2 * j;
      const float* wvp = swv + (hh * Cc + c) * HSc + 2 * j;
      q0 += hv * wqp[0]; q1 += hv * wqp[1];
      k0 += hv * wkp[0]; k1 += hv * wkp[1];
      v0 += hv * wvp[0]; v1 += hv * wvp[1];
    }
    long base = ((long)(bb * Hc + hh) * Tc + tt) * HSc;
    ((float2*)(q + base))[j] = make_float2(q0, q1);
    ((float2*)(k + base))[j] = make_float2(k0, k1);
    ((float2*)(v + base))[j] = make_float2(v0, v1);
  }
}

// ---------------------------------------------------------------------------
// K1) x = tok_emb[idx] + pos_emb ; h = LN1(x) ; q,k,v = h @ W  (layer 0)
//     4 lanes per token: 64 tokens per 256-thr block, 512 blocks.
// ---------------------------------------------------------------------------
__global__ __launch_bounds__(256) void embed_ln_qkv_kernel(
    const int* __restrict__ idx, const float* __restrict__ tok,
    const float* __restrict__ pos,
    const float* __restrict__ wq, const float* __restrict__ wk,
    const float* __restrict__ wv,
    const float* __restrict__ g, const float* __restrict__ b,
    float* __restrict__ x, float* __restrict__ q, float* __restrict__ k,
    float* __restrict__ v) {
  __shared__ float swq[256], swk[256], swv[256], sg[Cc], sb[Cc];
  int tid = threadIdx.x;
  swq[tid] = wq[tid];
  swk[tid] = wk[tid];
  swv[tid] = wv[tid];
  if (tid < Cc) { sg[tid] = g[tid]; sb[tid] = b[tid]; }
  __syncthreads();

  int tk = blockIdx.x * 64 + (tid >> 2);
  int j  = tid & 3;
  int tt = tk & (Tc - 1);
  int bb = tk >> 11;
  int id = idx[tk];
  float xr[Cc];
  const float4* te = (const float4*)(tok + id * Cc);
  const float4* pe = (const float4*)(pos + tt * Cc);
#pragma unroll
  for (int i = 0; i < 4; i++) {
    float4 a = te[i], p = pe[i];
    xr[4*i] = a.x + p.x; xr[4*i+1] = a.y + p.y;
    xr[4*i+2] = a.z + p.z; xr[4*i+3] = a.w + p.w;
  }
  ((float4*)(x + (long)tk * Cc))[j] =
      make_float4(xr[4*j], xr[4*j+1], xr[4*j+2], xr[4*j+3]);
  float h[Cc];
  layernorm16(xr, h, sg, sb);
  qkv_store_lane(h, swq, swk, swv, bb, tt, j, q, k, v);
}

// ---------------------------------------------------------------------------
// K2) Causal flash attention, K-chunk split, 4 queries/thread, packed f32.
//     Writes UNNORMALIZED partials (acc[8], l) per (query, chunk).
//     No max subtraction (|score| << 1 -> exp safe; softmax shift-invariant).
// ---------------------------------------------------------------------------
__global__ __launch_bounds__(256) void attn_kernel(
    const float* __restrict__ q, const float* __restrict__ k,
    const float* __restrict__ v, float* __restrict__ pacc,
    float* __restrict__ pl) {
  int bh = blockIdx.x;            // 0..31
  int ch = blockIdx.y;            // 0..15
  int qb = blockIdx.z;            // 0..1
  int k0 = ch * KC;
  if (k0 >= (qb + 1) * QB) return;       // chunk entirely in causal future

  __shared__ float sk[KC * HSc], sv[KC * HSc];
  int tid = threadIdx.x;
  {
    const float4* ksrc = (const float4*)(k + ((long)bh * Tc + k0) * HSc);
    const float4* vsrc = (const float4*)(v + ((long)bh * Tc + k0) * HSc);
    ((float4*)sk)[tid] = ksrc[tid];      // KC*HSc/4 == 256 == blockDim
    ((float4*)sv)[tid] = vsrc[tid];
  }
  __syncthreads();

  const float pre = 0.35355339059327373f * 1.4426950408889634f;
  int q0 = qb * QB + tid;         // queries q0 + 256*i
  f2 qr[4][4];
  f2 acc[4][4];
  float l[4] = {0.f, 0.f, 0.f, 0.f};
  int kmax[4];
#pragma unroll
  for (int i = 0; i < 4; i++) {
    int qi = q0 + 256 * i;
    const f2* qp = (const f2*)(q + ((long)bh * Tc + qi) * HSc);
#pragma unroll
    for (int jj = 0; jj < 4; jj++) {
      qr[i][jj] = qp[jj] * pre;
      acc[i][jj] = {0.f, 0.f};
    }
    int km = qi + 1 - k0;
    kmax[i] = km < 0 ? 0 : (km > KC ? KC : km);
  }

  const f2* skp = (const f2*)sk;
  const f2* svp = (const f2*)sv;

#define ATTN_STEP(u, MASKED)                                              \
  {                                                                       \
    f2 k0v = skp[(u)*4+0], k1v = skp[(u)*4+1],                            \
       k2v = skp[(u)*4+2], k3v = skp[(u)*4+3];                            \
    f2 v0v = svp[(u)*4+0], v1v = svp[(u)*4+1],                            \
       v2v = svp[(u)*4+2], v3v = svp[(u)*4+3];                            \
    _Pragma("unroll")                                                     \
    for (int i = 0; i < 4; i++) {                                         \
      f2 d = qr[i][0] * k0v;                                              \
      d += qr[i][1] * k1v;                                                \
      d += qr[i][2] * k2v;                                                \
      d += qr[i][3] * k3v;                                                \
      float s = d.x + d.y;                                                \
      float p = __builtin_amdgcn_exp2f(s);                                \
      if (MASKED) p = ((u) < kmax[i]) ? p : 0.f;                          \
      l[i] += p;                                                          \
      acc[i][0] += p * v0v;                                               \
      acc[i][1] += p * v1v;                                               \
      acc[i][2] += p * v2v;                                               \
      acc[i][3] += p * v3v;                                               \
    }                                                                     \
  }

  bool full = (k0 + KC) <= qb * QB;   // all 4 queries see every key in chunk
  if (full) {
    for (int u = 0; u < KC; u++) ATTN_STEP(u, false)
  } else {
    int bound = kmax[3];
    for (int u = 0; u < bound; u++) ATTN_STEP(u, true)
  }
#undef ATTN_STEP

  long rec = (long)(bh * NCH + ch) * Tc;
#pragma unroll
  for (int i = 0; i < 4; i++) {
    if (kmax[i] > 0) {
      int qi = q0 + 256 * i;
      float4* pa = (float4*)(pacc + (rec + qi) * 8);
      pa[0] = make_float4(acc[i][0].x, acc[i][0].y, acc[i][1].x, acc[i][1].y);
      pa[1] = make_float4(acc[i][2].x, acc[i][2].y, acc[i][3].x, acc[i][3].y);
      pl[rec + qi] = l[i];
    }
  }
}

// ---------------------------------------------------------------------------
// 4-lane cooperative tail: reduce partials -> o ; x += o@wo^T ; x += MLP(LN2)
// Lane roles (j = lane&3):
//   A: head j&1, chunks (j>>1)::2   -> shfl_xor combine
//   B: proj outputs c = 4j..4j+3    -> shfl_xor replicate
//   C: MLP hidden units j*16..+15   -> shfl_xor combine
// LDS layouts: swo [16][17] padded, sw1 [64][17] padded, sw2 [16][64].
// xr: in = x row, out = final residual row (all lanes full).
// ---------------------------------------------------------------------------
__device__ inline void coop_tail(
    const float* __restrict__ pacc, const float* __restrict__ pl,
    const float* swo, const float* sw1, const float* sw2,
    const float* sg2, const float* sb2, int bb, int tt, int j, float* xr) {
  // --- A: attention partial reduce
  int hh  = j & 1;
  int bh  = bb * Hc + hh;
  int nch = tt / KC + 1;
  float o8[8] = {0,0,0,0,0,0,0,0};
  float l = 0.f;
  for (int ch = (j >> 1); ch < nch; ch += 2) {
    long rec = (long)(bh * NCH + ch) * Tc + tt;
    const float4* pa = (const float4*)(pacc + rec * 8);
    float4 a = pa[0], b = pa[1];
    o8[0]+=a.x; o8[1]+=a.y; o8[2]+=a.z; o8[3]+=a.w;
    o8[4]+=b.x; o8[5]+=b.y; o8[6]+=b.z; o8[7]+=b.w;
    l += pl[rec];
  }
#pragma unroll
  for (int s = 0; s < 8; s++) o8[s] += shx(o8[s], 2);
  l += shx(l, 2);
  float inv = 1.f / l;
  float own[8], oth[8];
#pragma unroll
  for (int s = 0; s < 8; s++) own[s] = o8[s] * inv;
#pragma unroll
  for (int s = 0; s < 8; s++) oth[s] = shx(own[s], 1);
  float orow[Cc];
#pragma unroll
  for (int s = 0; s < 8; s++) {
    orow[s]     = (hh == 0) ? own[s] : oth[s];
    orow[8 + s] = (hh == 0) ? oth[s] : own[s];
  }
  // --- B: proj, c = 4j..4j+3
  float xc[4];
#pragma unroll
  for (int qq = 0; qq < 4; qq++) {
    int c = 4 * j + qq;
    float acc = xr[c];
#pragma unroll
    for (int kk = 0; kk < Cc; kk++) acc += orow[kk] * swo[c * 17 + kk];
    xc[qq] = acc;
  }
  {
    float p[4];
#pragma unroll
    for (int qq = 0; qq < 4; qq++) p[qq] = shx(xc[qq], 1);
    bool lo = (j & 1) == 0;
    float a8[8], b8[8];
#pragma unroll
    for (int qq = 0; qq < 4; qq++) {
      a8[qq]     = lo ? xc[qq] : p[qq];
      a8[4 + qq] = lo ? p[qq] : xc[qq];
    }
#pragma unroll
    for (int s = 0; s < 8; s++) b8[s] = shx(a8[s], 2);
    bool lo2 = (j & 2) == 0;
#pragma unroll
    for (int s = 0; s < 8; s++) {
      xr[s]     = lo2 ? a8[s] : b8[s];
      xr[8 + s] = lo2 ? b8[s] : a8[s];
    }
  }
  // --- C: MLP, hidden units j*16..j*16+15
  float h[Cc];
  layernorm16(xr, h, sg2, sb2);
  float r[Cc];
#pragma unroll
  for (int c = 0; c < Cc; c++) r[c] = 0.f;
#pragma unroll
  for (int i = 0; i < 16; i++) {
    int jj = j * 16 + i;
    float acc = 0.f;
#pragma unroll
    for (int c = 0; c < Cc; c++) acc += h[c] * sw1[jj * 17 + c];
    acc = fmaxf(acc, 0.f);
#pragma unroll
    for (int c = 0; c < Cc; c++) r[c] += acc * sw2[c * 64 + jj];
  }
#pragma unroll
  for (int c = 0; c < Cc; c++) r[c] += shx(r[c], 1);
#pragma unroll
  for (int c = 0; c < Cc; c++) r[c] += shx(r[c], 2);
#pragma unroll
  for (int c = 0; c < Cc; c++) xr[c] += r[c];
}

// ---------------------------------------------------------------------------
// K3) layer-l epilogue + layer-(l+1) LN1+QKV  (4-lane coop, 512 blocks)
// ---------------------------------------------------------------------------
__global__ __launch_bounds__(256) void red_mid_kernel(
    const float* __restrict__ pacc, const float* __restrict__ pl,
    const float* __restrict__ wo, const float* __restrict__ g2,
    const float* __restrict__ b2, const float* __restrict__ w1,
    const float* __restrict__ w2,
    const float* __restrict__ wq, const float* __restrict__ wk,
    const float* __restrict__ wv, const float* __restrict__ g1,
    const float* __restrict__ b1,
    float* __restrict__ x, float* __restrict__ q, float* __restrict__ k,
    float* __restrict__ v) {
  __shared__ float swo[16 * 17], sw1[64 * 17], sw2[1024];
  __shared__ float swq[256], swk[256], swv[256];
  __shared__ float sg2[Cc], sb2[Cc], sg1[Cc], sb1[Cc];
  int tid = threadIdx.x;
  swq[tid] = wq[tid]; swk[tid] = wk[tid]; swv[tid] = wv[tid];
  { int rr = tid >> 4, c = tid & 15; swo[rr * 17 + c] = wo[tid]; }
#pragma unroll
  for (int t = tid; t < 1024; t += 256) {
    int jj = t >> 4, c = t & 15;
    sw1[jj * 17 + c] = w1[t];
    sw2[t] = w2[t];
  }
  if (tid < Cc) {
    sg2[tid] = g2[tid]; sb2[tid] = b2[tid];
    sg1[tid] = g1[tid]; sb1[tid] = b1[tid];
  }
  __syncthreads();

  int tk = blockIdx.x * 64 + (tid >> 2);
  int j  = tid & 3;
  int bb = tk >> 11, tt = tk & (Tc - 1);
  float xr[Cc];
  const float4* xp = (const float4*)(x + (long)tk * Cc);
#pragma unroll
  for (int i = 0; i < 4; i++) {
    float4 a = xp[i];
    xr[4*i]=a.x; xr[4*i+1]=a.y; xr[4*i+2]=a.z; xr[4*i+3]=a.w;
  }
  coop_tail(pacc, pl, swo, sw1, sw2, sg2, sb2, bb, tt, j, xr);
  ((float4*)(x + (long)tk * Cc))[j] =
      make_float4(xr[4*j], xr[4*j+1], xr[4*j+2], xr[4*j+3]);
  float h[Cc];
  layernorm16(xr, h, sg1, sb1);
  qkv_store_lane(h, swq, swk, swv, bb, tt, j, q, k, v);
}

// ---------------------------------------------------------------------------
// K5) final-layer epilogue + LNf + tied lm_head  (4-lane coop + head phase)
// ---------------------------------------------------------------------------
__global__ __launch_bounds__(256) void red_lnf_head_kernel(
    const float* __restrict__ pacc, const float* __restrict__ pl,
    const float* __restrict__ wo, const float* __restrict__ g2,
    const float* __restrict__ b2, const float* __restrict__ w1,
    const float* __restrict__ w2, const float* __restrict__ gf,
    const float* __restrict__ bf,
    const float* __restrict__ x, const float* __restrict__ tok,
    float* __restrict__ out) {
  __shared__ float swo[16 * 17], sw1[64 * 17], sw2[1024];
  __shared__ float sg2[Cc], sb2[Cc], sgf[Cc], sbf[Cc];
  __shared__ float sh[64 * Cc];
  int tid = threadIdx.x;
  { int rr = tid >> 4, c = tid & 15; swo[rr * 17 + c] = wo[tid]; }
#pragma unroll
  for (int t = tid; t < 1024; t += 256) {
    int jj = t >> 4, c = t & 15;
    sw1[jj * 17 + c] = w1[t];
    sw2[t] = w2[t];
  }
  if (tid < Cc) {
    sg2[tid] = g2[tid]; sb2[tid] = b2[tid];
    sgf[tid] = gf[tid]; sbf[tid] = bf[tid];
  }
  __syncthreads();

  int tk = blockIdx.x * 64 + (tid >> 2);
  int j  = tid & 3;
  int bb = tk >> 11, tt = tk & (Tc - 1);
  float xr[Cc];
  const float4* xp = (const float4*)(x + (long)tk * Cc);
#pragma unroll
  for (int i = 0; i < 4; i++) {
    float4 a = xp[i];
    xr[4*i]=a.x; xr[4*i+1]=a.y; xr[4*i+2]=a.z; xr[4*i+3]=a.w;
  }
  coop_tail(pacc, pl, swo, sw1, sw2, sg2, sb2, bb, tt, j, xr);
  float h[Cc];
  layernorm16(xr, h, sgf, sbf);
  ((float4*)(sh + (tid >> 2) * Cc))[j] =
      make_float4(h[4*j], h[4*j+1], h[4*j+2], h[4*j+3]);
  __syncthreads();

  // head phase: thread = vocab id, 64 tokens from LDS (broadcast reads)
  float4 e0, e1, e2, e3;
  {
    const float4* ep = (const float4*)(tok + tid * Cc);
    e0 = ep[0]; e1 = ep[1]; e2 = ep[2]; e3 = ep[3];
  }
  int row0 = blockIdx.x * 64;
#pragma unroll 4
  for (int t = 0; t < 64; t++) {
    const float4* hp = (const float4*)(sh + t * Cc);
    float4 h0 = hp[0], h1 = hp[1], h2 = hp[2], h3 = hp[3];
    float acc = h0.x*e0.x + h0.y*e0.y + h0.z*e0.z + h0.w*e0.w
              + h1.x*e1.x + h1.y*e1.y + h1.z*e1.z + h1.w*e1.w
              + h2.x*e2.x + h2.y*e2.y + h2.z*e2.z + h2.w*e2.w
              + h3.x*e3.x + h3.y*e3.y + h3.z*e3.z + h3.w*e3.w;
    out[(long)(row0 + t) * Vc + tid] = acc;
  }
}

// ---------------------------------------------------------------------------
// launcher
// ---------------------------------------------------------------------------
extern "C" void kernel_launch(void* const* d_in, const int* in_sizes, int n_in,
                              void* d_out, int out_size, void* d_ws,
                              size_t ws_size, hipStream_t stream) {
  const int*   idx  = (const int*)  d_in[0];
  const float* tok  = (const float*)d_in[1];
  const float* pos  = (const float*)d_in[2];
  const float* wq   = (const float*)d_in[3];
  const float* wk   = (const float*)d_in[4];
  const float* wv   = (const float*)d_in[5];
  const float* wo   = (const float*)d_in[6];
  const float* ln1g = (const float*)d_in[7];
  const float* ln1b = (const float*)d_in[8];
  const float* ln2g = (const float*)d_in[9];
  const float* ln2b = (const float*)d_in[10];
  const float* w1   = (const float*)d_in[11];
  const float* w2   = (const float*)d_in[12];
  const float* lnfg = (const float*)d_in[13];
  const float* lnfb = (const float*)d_in[14];
  float* out = (float*)d_out;

  // workspace layout (floats):
  // x: 2MB | q,k,v: 2MB each | pacc: 33.5MB | pl: 4MB  -> ~45.5MB total
  float* x    = (float*)d_ws;
  float* q    = x + (long)BT * Cc;
  float* k    = q + (long)Bc * Hc * Tc * HSc;
  float* v    = k + (long)Bc * Hc * Tc * HSc;
  float* pacc = v + (long)Bc * Hc * Tc * HSc;
  float* pl   = pacc + (long)Bc * Hc * NCH * Tc * HSc;

  dim3 agrid(Bc * Hc, NCH, NQB);

  embed_ln_qkv_kernel<<<BT / 64, 256, 0, stream>>>(
      idx, tok, pos, wq, wk, wv, ln1g, ln1b, x, q, k, v);
  attn_kernel<<<agrid, 256, 0, stream>>>(q, k, v, pacc, pl);
  red_mid_kernel<<<BT / 64, 256, 0, stream>>>(
      pacc, pl, wo, ln2g, ln2b, w1, w2,
      wq + Hc * Cc * HSc, wk + Hc * Cc * HSc, wv + Hc * Cc * HSc,
      ln1g + Cc, ln1b + Cc, x, q, k, v);
  attn_kernel<<<agrid, 256, 0, stream>>>(q, k, v, pacc, pl);
  red_lnf_head_kernel<<<BT / 64, 256, 0, stream>>>(
      pacc, pl, wo + Cc * Cc, ln2g + Cc, ln2b + Cc,
      w1 + 4 * Cc * Cc, w2 + 4 * Cc * Cc, lnfg, lnfb, x, tok, out);
}